// Round 1
// baseline (442.806 us; speedup 1.0000x reference)
//
#include <hip/hip_runtime.h>
#include <math.h>

constexpr int T_TOK = 16384;
constexpr int HDIM  = 2048;
constexpr int NEXP  = 64;
constexpr int TPB   = 64;            // tokens per block
constexpr int NWAVE = 8;             // waves per block
constexpr int HPW   = HDIM / NWAVE;  // 256 h per wave
constexpr int CH    = 32;            // h chunk per wave per k-iter
constexpr int NK    = HPW / CH;      // 8 k-iterations

__global__ __launch_bounds__(512, 2)
void moe_router_kernel(const float* __restrict__ X,
                       const float* __restrict__ Wg,
                       const float* __restrict__ Bg,
                       float* __restrict__ out)
{
    // 64 KiB LDS: during K loop = X tile (64 tokens x 256 cols, XOR-swizzled);
    // after K loop = partial-logit buffer [64 experts][4 slots][64 tokens].
    __shared__ float lds[TPB * 256];

    const int tid  = threadIdx.x;
    const int lane = tid & 63;
    const int wv   = __builtin_amdgcn_readfirstlane(tid >> 6);  // wave id, provably uniform
    const int tok0 = blockIdx.x * TPB;
    const int swz  = lane & 31;

    float acc[NEXP];
#pragma unroll
    for (int e = 0; e < NEXP; ++e) acc[e] = 0.0f;

    for (int k = 0; k < NK; ++k) {
        __syncthreads();   // previous iteration's readers done before overwrite
        // ---- stage X tile: tile col c = ww*32 + j  <->  global h = ww*256 + k*32 + j
#pragma unroll
        for (int m = 0; m < 8; ++m) {
            int f   = m * 512 + tid;       // float4 slot 0..4095, lane-consecutive
            int j4  = f & 7;               // quad within 32-float window
            int ww  = (f >> 3) & 7;        // which wave's window
            int row = f >> 6;              // token row 0..63
            const float4 v = *(const float4*)(X + (size_t)(tok0 + row) * HDIM
                                              + ww * HPW + k * CH + j4 * 4);
            int cbase  = ww * CH + j4 * 4;
            int rsw    = row & 31;
            float* dst = lds + row * 256;
            dst[(cbase + 0) ^ rsw] = v.x;
            dst[(cbase + 1) ^ rsw] = v.y;
            dst[(cbase + 2) ^ rsw] = v.z;
            dst[(cbase + 3) ^ rsw] = v.w;
        }
        __syncthreads();
        // ---- each lane pulls its token's 32-float window (conflict-free: 2 lanes/bank)
        float x[CH];
        {
            const float* src = lds + lane * 256;
            const int cb = wv * CH;
#pragma unroll
            for (int j = 0; j < CH; ++j)
                x[j] = src[(cb + j) ^ swz];
        }
        // ---- 64 experts; W comes in through scalar cache (wave-uniform address)
        const float* wbase = Wg + wv * HPW + k * CH;
#pragma unroll
        for (int e = 0; e < NEXP; ++e) {
            const float* wp = wbase + (size_t)e * HDIM;
            float s0 = 0.f, s1 = 0.f, s2 = 0.f, s3 = 0.f;
#pragma unroll
            for (int j = 0; j < CH; j += 4) {
                s0 = fmaf(x[j+0], wp[j+0], s0);
                s1 = fmaf(x[j+1], wp[j+1], s1);
                s2 = fmaf(x[j+2], wp[j+2], s2);
                s3 = fmaf(x[j+3], wp[j+3], s3);
            }
            acc[e] += (s0 + s1) + (s2 + s3);
        }
    }

    // ---- cross-wave reduction, two phases so the buffer stays 64 KiB
    __syncthreads();
    if (wv < 4) {
#pragma unroll
        for (int e = 0; e < NEXP; ++e) lds[e * 256 + wv * 64 + lane] = acc[e];
    }
    __syncthreads();
    if (wv >= 4) {
#pragma unroll
        for (int e = 0; e < NEXP; ++e) lds[e * 256 + (wv - 4) * 64 + lane] += acc[e];
    }
    __syncthreads();

    // ---- epilogue: 8 tokens per wave on lanes 0..7 (all 8 SIMDs busy)
    if (lane < 8) {
        const int tk = wv * 8 + lane;
        const int t  = tok0 + tk;
        float lg[NEXP];
#pragma unroll
        for (int e = 0; e < NEXP; ++e) {
            lg[e] = ((lds[e*256 +   0 + tk] + lds[e*256 +  64 + tk]) +
                     (lds[e*256 + 128 + tk] + lds[e*256 + 192 + tk])) + Bg[e];
        }
        // raw logits
        float* outL = out + (size_t)t * NEXP;
#pragma unroll
        for (int e = 0; e < NEXP; e += 4) {
            float4 v = make_float4(lg[e], lg[e+1], lg[e+2], lg[e+3]);
            *(float4*)(outL + e) = v;
        }
        // softmax in fp32 (exp(x-max)/sum), normalized probs for top-k like the ref
        float mx = lg[0];
#pragma unroll
        for (int e = 1; e < NEXP; ++e) mx = fmaxf(mx, lg[e]);
        float S = 0.f;
#pragma unroll
        for (int e = 0; e < NEXP; ++e) { lg[e] = expf(lg[e] - mx); S += lg[e]; }
#pragma unroll
        for (int e = 0; e < NEXP; ++e) lg[e] = lg[e] / S;

        // top-2, first-occurrence-on-tie (stable, matches lax.top_k)
        float v1 = lg[0]; int i1 = 0;
        float v2 = -1.0f; int i2 = 0;
#pragma unroll
        for (int e = 1; e < NEXP; ++e) {
            float rv = lg[e];
            bool g1 = rv > v1;
            bool g2 = rv > v2;
            float nv2 = g1 ? v1 : (g2 ? rv : v2);
            int   ni2 = g1 ? i1 : (g2 ? e  : i2);
            v2 = nv2; i2 = ni2;
            v1 = g1 ? rv : v1;
            i1 = g1 ? e  : i1;
        }
        float den = v1 + v2;
        float w1 = v1 / den, w2 = v2 / den;

        float* outW = out + (size_t)T_TOK * NEXP;          // 1,048,576
        float* outS = outW + (size_t)T_TOK * 2;            // +32,768
        float* outM = outS + (size_t)T_TOK * 2;            // +32,768
        outW[2*t+0] = w1;        outW[2*t+1] = w2;
        outS[2*t+0] = (float)i1; outS[2*t+1] = (float)i2;

        float* mrow = outM + (size_t)t * 2 * NEXP;
#pragma unroll
        for (int e = 0; e < NEXP; e += 4) {
            float4 a = make_float4(e+0==i1?1.f:0.f, e+1==i1?1.f:0.f,
                                   e+2==i1?1.f:0.f, e+3==i1?1.f:0.f);
            *(float4*)(mrow + e) = a;
            float4 b = make_float4(e+0==i2?1.f:0.f, e+1==i2?1.f:0.f,
                                   e+2==i2?1.f:0.f, e+3==i2?1.f:0.f);
            *(float4*)(mrow + NEXP + e) = b;
        }
    }
}

extern "C" void kernel_launch(void* const* d_in, const int* in_sizes, int n_in,
                              void* d_out, int out_size, void* d_ws, size_t ws_size,
                              hipStream_t stream)
{
    const float* X = (const float*)d_in[0];
    const float* W = (const float*)d_in[1];
    const float* B = (const float*)d_in[2];
    float* out     = (float*)d_out;

    dim3 grid(T_TOK / TPB);   // 256 blocks -> 1 block (8 waves) per CU
    dim3 block(512);
    hipLaunchKernelGGL(moe_router_kernel, grid, block, 0, stream, X, W, B, out);
}

// Round 2
// 317.320 us; speedup vs baseline: 1.3955x; 1.3955x over previous
//
#include <hip/hip_runtime.h>
#include <math.h>

constexpr int T_TOK = 16384;
constexpr int HDIM  = 2048;
constexpr int NEXP  = 64;
constexpr int TPB   = 64;            // tokens per block (= lanes)
constexpr int NWAVE = 8;             // waves per block
constexpr int HPW   = HDIM / NWAVE;  // 256 h per wave (K-split across waves)
constexpr int CH    = 8;             // h per wave per k-step
constexpr int NK    = HPW / CH;      // 32 k-steps
constexpr int XPITCH = NWAVE * CH + 1;   // 65 floats, bank-conflict-free rows

__global__ __launch_bounds__(512, 2)
void moe_router_kernel(const float* __restrict__ X,
                       const float* __restrict__ Wg,
                       const float* __restrict__ Bg,
                       float* __restrict__ out)
{
    // Staging region (33 KB) unioned with the cross-wave reduction buffer (64 KB).
    __shared__ union {
        struct {
            float xt[TPB * XPITCH];          // 64 tok x 65  (cols = wv*8 + j)
            float wt[NWAVE * NEXP * CH];     // [wv][e][8]
        } s;
        float red[NEXP * 4 * TPB];           // [e][slot 0..3][tok]
    } u;

    const int tid  = threadIdx.x;
    const int lane = tid & 63;
    const int wv   = __builtin_amdgcn_readfirstlane(tid >> 6);  // uniform wave id
    const int tok0 = blockIdx.x * TPB;

    float acc[NEXP];
#pragma unroll
    for (int e = 0; e < NEXP; ++e) acc[e] = 0.0f;

    for (int k = 0; k < NK; ++k) {
        __syncthreads();   // previous step's readers done before overwrite

        // ---- stage X tile: 1024 float4, 2 per thread.
        // f: tok=f>>4, q=f&15 ; tile col c=q*4+i  <->  global h=(q>>1)*256 + k*8 + (q&1)*4 + i
#pragma unroll
        for (int m = 0; m < 2; ++m) {
            int f   = m * 512 + tid;
            int tok = f >> 4;
            int q   = f & 15;
            const float4 v = *(const float4*)(X + (size_t)(tok0 + tok) * HDIM
                                              + (q >> 1) * HPW + k * CH + (q & 1) * 4);
            float* dst = u.s.xt + tok * XPITCH + q * 4;
            dst[0] = v.x; dst[1] = v.y; dst[2] = v.z; dst[3] = v.w;
        }
        // ---- stage W chunk: 1024 float4, 2 per thread -> wt[wv][e][8]
#pragma unroll
        for (int m = 0; m < 2; ++m) {
            int f    = m * 512 + tid;
            int wvd  = f >> 7;
            int e    = (f >> 1) & 63;
            int half = f & 1;
            const float4 v = *(const float4*)(Wg + (size_t)e * HDIM
                                              + wvd * HPW + k * CH + half * 4);
            *(float4*)(u.s.wt + wvd * (NEXP * CH) + e * CH + half * 4) = v;
        }
        __syncthreads();

        // ---- per-lane x (token row, conflict-free via 65 pitch)
        float x[CH];
        {
            const float* src = u.s.xt + lane * XPITCH + wv * CH;
#pragma unroll
            for (int j = 0; j < CH; ++j) x[j] = src[j];
        }
        // ---- 64 experts; W via wave-uniform LDS broadcast b128 (2 reads : 8 fmas)
        const float* wp = u.s.wt + wv * (NEXP * CH);
#pragma unroll
        for (int e = 0; e < NEXP; ++e) {
            const float4 w0 = *(const float4*)(wp + e * CH);
            const float4 w1 = *(const float4*)(wp + e * CH + 4);
            float a = acc[e];
            a = fmaf(x[0], w0.x, a);
            a = fmaf(x[1], w0.y, a);
            a = fmaf(x[2], w0.z, a);
            a = fmaf(x[3], w0.w, a);
            a = fmaf(x[4], w1.x, a);
            a = fmaf(x[5], w1.y, a);
            a = fmaf(x[6], w1.z, a);
            a = fmaf(x[7], w1.w, a);
            acc[e] = a;
        }
    }

    // ---- cross-wave K-reduction (round-1 proven pattern)
    __syncthreads();
    if (wv < 4) {
#pragma unroll
        for (int e = 0; e < NEXP; ++e) u.red[e * 256 + wv * 64 + lane] = acc[e];
    }
    __syncthreads();
    if (wv >= 4) {
#pragma unroll
        for (int e = 0; e < NEXP; ++e) u.red[e * 256 + (wv - 4) * 64 + lane] += acc[e];
    }
    __syncthreads();

    // ---- epilogue: 8 tokens per wave on lanes 0..7 (identical to round 1)
    if (lane < 8) {
        const int tk = wv * 8 + lane;
        const int t  = tok0 + tk;
        float lg[NEXP];
#pragma unroll
        for (int e = 0; e < NEXP; ++e) {
            lg[e] = ((u.red[e*256 +   0 + tk] + u.red[e*256 +  64 + tk]) +
                     (u.red[e*256 + 128 + tk] + u.red[e*256 + 192 + tk])) + Bg[e];
        }
        float* outL = out + (size_t)t * NEXP;
#pragma unroll
        for (int e = 0; e < NEXP; e += 4) {
            float4 v = make_float4(lg[e], lg[e+1], lg[e+2], lg[e+3]);
            *(float4*)(outL + e) = v;
        }
        float mx = lg[0];
#pragma unroll
        for (int e = 1; e < NEXP; ++e) mx = fmaxf(mx, lg[e]);
        float S = 0.f;
#pragma unroll
        for (int e = 0; e < NEXP; ++e) { lg[e] = expf(lg[e] - mx); S += lg[e]; }
#pragma unroll
        for (int e = 0; e < NEXP; ++e) lg[e] = lg[e] / S;

        float v1 = lg[0]; int i1 = 0;
        float v2 = -1.0f; int i2 = 0;
#pragma unroll
        for (int e = 1; e < NEXP; ++e) {
            float rv = lg[e];
            bool g1 = rv > v1;
            bool g2 = rv > v2;
            float nv2 = g1 ? v1 : (g2 ? rv : v2);
            int   ni2 = g1 ? i1 : (g2 ? e  : i2);
            v2 = nv2; i2 = ni2;
            v1 = g1 ? rv : v1;
            i1 = g1 ? e  : i1;
        }
        float den = v1 + v2;
        float w1 = v1 / den, w2 = v2 / den;

        float* outW = out + (size_t)T_TOK * NEXP;
        float* outS = outW + (size_t)T_TOK * 2;
        float* outM = outS + (size_t)T_TOK * 2;
        outW[2*t+0] = w1;        outW[2*t+1] = w2;
        outS[2*t+0] = (float)i1; outS[2*t+1] = (float)i2;

        float* mrow = outM + (size_t)t * 2 * NEXP;
#pragma unroll
        for (int e = 0; e < NEXP; e += 4) {
            float4 a = make_float4(e+0==i1?1.f:0.f, e+1==i1?1.f:0.f,
                                   e+2==i1?1.f:0.f, e+3==i1?1.f:0.f);
            *(float4*)(mrow + e) = a;
            float4 b = make_float4(e+0==i2?1.f:0.f, e+1==i2?1.f:0.f,
                                   e+2==i2?1.f:0.f, e+3==i2?1.f:0.f);
            *(float4*)(mrow + NEXP + e) = b;
        }
    }
}

extern "C" void kernel_launch(void* const* d_in, const int* in_sizes, int n_in,
                              void* d_out, int out_size, void* d_ws, size_t ws_size,
                              hipStream_t stream)
{
    const float* X = (const float*)d_in[0];
    const float* W = (const float*)d_in[1];
    const float* B = (const float*)d_in[2];
    float* out     = (float*)d_out;

    dim3 grid(T_TOK / TPB);   // 256 blocks
    dim3 block(512);
    hipLaunchKernelGGL(moe_router_kernel, grid, block, 0, stream, X, W, B, out);
}

// Round 3
// 223.466 us; speedup vs baseline: 1.9815x; 1.4200x over previous
//
#include <hip/hip_runtime.h>
#include <math.h>

constexpr int T_TOK = 16384;
constexpr int HDIM  = 2048;
constexpr int NEXP  = 64;
constexpr int TPB   = 64;            // tokens per block
constexpr int NWAVE = 8;
constexpr int KPW   = HDIM / NWAVE;  // 256 k per wave
constexpr int KSTEP = 32;
constexpr int NKS   = KPW / KSTEP;   // 8 k-steps

typedef __attribute__((ext_vector_type(8))) short v8s;   // 8 bf16 (4 VGPRs)
typedef __attribute__((ext_vector_type(4))) float v4f;   // 4 fp32 acc

#define MFMA_BF16 __builtin_amdgcn_mfma_f32_16x16x32_bf16

// Dekker-style truncation split: x = h + m + l exactly to ~24 mantissa bits.
static __device__ __forceinline__ void split3(float x, unsigned short& h,
                                              unsigned short& m, unsigned short& l)
{
    unsigned u0 = __float_as_uint(x);
    h = (unsigned short)(u0 >> 16);
    float r1 = x - __uint_as_float(u0 & 0xFFFF0000u);     // exact
    unsigned u1 = __float_as_uint(r1);
    m = (unsigned short)(u1 >> 16);
    float r2 = r1 - __uint_as_float(u1 & 0xFFFF0000u);    // exact
    l = (unsigned short)(__float_as_uint(r2) >> 16);
}

static __device__ __forceinline__ void frag3(const float4& x0, const float4& x1,
                                             v8s& h, v8s& m, v8s& l)
{
    unsigned short sh, sm, sl;
    split3(x0.x, sh, sm, sl); h[0]=(short)sh; m[0]=(short)sm; l[0]=(short)sl;
    split3(x0.y, sh, sm, sl); h[1]=(short)sh; m[1]=(short)sm; l[1]=(short)sl;
    split3(x0.z, sh, sm, sl); h[2]=(short)sh; m[2]=(short)sm; l[2]=(short)sl;
    split3(x0.w, sh, sm, sl); h[3]=(short)sh; m[3]=(short)sm; l[3]=(short)sl;
    split3(x1.x, sh, sm, sl); h[4]=(short)sh; m[4]=(short)sm; l[4]=(short)sl;
    split3(x1.y, sh, sm, sl); h[5]=(short)sh; m[5]=(short)sm; l[5]=(short)sl;
    split3(x1.z, sh, sm, sl); h[6]=(short)sh; m[6]=(short)sm; l[6]=(short)sl;
    split3(x1.w, sh, sm, sl); h[7]=(short)sh; m[7]=(short)sm; l[7]=(short)sl;
}

// swizzled expert column for the LDS reduction buffer (breaks 4-way write conflicts)
static __device__ __forceinline__ int swz_e(int tok, int e) {
    return e ^ (((tok >> 2) & 1) << 4);
}

__global__ __launch_bounds__(512, 2)
void moe_router_mfma(const float* __restrict__ X,
                     const float* __restrict__ Wg,
                     const float* __restrict__ Bg,
                     float* __restrict__ out)
{
    __shared__ float red[4][TPB][NEXP];    // 64 KiB, epilogue only

    const int tid  = threadIdx.x;
    const int lane = tid & 63;
    const int wv   = tid >> 6;             // wave id = k-slice
    const int r16  = lane & 15;
    const int q    = lane >> 4;            // quad id (k-chunk selector)
    const int tok0 = blockIdx.x * TPB;

    // A: lane reads X[tok0 + 16*mt + r16][wv*256 + ks*32 + q*8 .. +7]
    const float* pA = X  + (size_t)(tok0 + r16) * HDIM + wv * KPW + q * 8;
    // B: lane reads W[16*nt + r16][same k window]
    const float* pB = Wg + (size_t)r16 * HDIM + wv * KPW + q * 8;

    v4f acc[4][4];
#pragma unroll
    for (int mt = 0; mt < 4; ++mt)
#pragma unroll
        for (int nt = 0; nt < 4; ++nt)
            acc[mt][nt] = (v4f){0.f, 0.f, 0.f, 0.f};

    float4 a0[4], a1[4], b0[4], b1[4];
#pragma unroll
    for (int mt = 0; mt < 4; ++mt) {
        const float* p = pA + (size_t)mt * 16 * HDIM;
        a0[mt] = *(const float4*)p;
        a1[mt] = *(const float4*)(p + 4);
    }
#pragma unroll
    for (int nt = 0; nt < 4; ++nt) {
        const float* p = pB + (size_t)nt * 16 * HDIM;
        b0[nt] = *(const float4*)p;
        b1[nt] = *(const float4*)(p + 4);
    }

    for (int ks = 0; ks < NKS; ++ks) {
        // ---- split current fp32 buffers into bf16 frag triples
        v8s Ah[4], Am[4], Al[4], Bh[4], Bm[4], Bl[4];
#pragma unroll
        for (int mt = 0; mt < 4; ++mt) frag3(a0[mt], a1[mt], Ah[mt], Am[mt], Al[mt]);
#pragma unroll
        for (int nt = 0; nt < 4; ++nt) frag3(b0[nt], b1[nt], Bh[nt], Bm[nt], Bl[nt]);

        // ---- prefetch next k-step (covers HBM latency under the MFMA block)
        if (ks < NKS - 1) {
            const int off = (ks + 1) * KSTEP;
#pragma unroll
            for (int mt = 0; mt < 4; ++mt) {
                const float* p = pA + (size_t)mt * 16 * HDIM + off;
                a0[mt] = *(const float4*)p;
                a1[mt] = *(const float4*)(p + 4);
            }
#pragma unroll
            for (int nt = 0; nt < 4; ++nt) {
                const float* p = pB + (size_t)nt * 16 * HDIM + off;
                b0[nt] = *(const float4*)p;
                b1[nt] = *(const float4*)(p + 4);
            }
        }

        // ---- 6-product split GEMM: hh + hm + mh + hl + lh + mm
#pragma unroll
        for (int mt = 0; mt < 4; ++mt)
#pragma unroll
            for (int nt = 0; nt < 4; ++nt) {
                v4f a = acc[mt][nt];
                a = MFMA_BF16(Ah[mt], Bh[nt], a, 0, 0, 0);
                a = MFMA_BF16(Ah[mt], Bm[nt], a, 0, 0, 0);
                a = MFMA_BF16(Am[mt], Bh[nt], a, 0, 0, 0);
                a = MFMA_BF16(Ah[mt], Bl[nt], a, 0, 0, 0);
                a = MFMA_BF16(Al[mt], Bh[nt], a, 0, 0, 0);
                a = MFMA_BF16(Am[mt], Bm[nt], a, 0, 0, 0);
                acc[mt][nt] = a;
            }
    }

    // ---- cross-wave K reduction: 4 slots, two phases
    // C/D layout: col(expert-local) = lane&15, row(token-local) = q*4 + r
    if (wv < 4) {
#pragma unroll
        for (int mt = 0; mt < 4; ++mt)
#pragma unroll
            for (int nt = 0; nt < 4; ++nt)
#pragma unroll
                for (int r = 0; r < 4; ++r) {
                    int tok = 16 * mt + q * 4 + r;
                    int e   = 16 * nt + r16;
                    red[wv][tok][swz_e(tok, e)] = acc[mt][nt][r];
                }
    }
    __syncthreads();
    if (wv >= 4) {
#pragma unroll
        for (int mt = 0; mt < 4; ++mt)
#pragma unroll
            for (int nt = 0; nt < 4; ++nt)
#pragma unroll
                for (int r = 0; r < 4; ++r) {
                    int tok = 16 * mt + q * 4 + r;
                    int e   = 16 * nt + r16;
                    red[wv - 4][tok][swz_e(tok, e)] += acc[mt][nt][r];
                }
    }
    __syncthreads();

    // ---- epilogue: 8 tokens/wave on lanes 0..7 (round-2 proven)
    if (lane < 8) {
        const int tk = wv * 8 + lane;
        const int t  = tok0 + tk;
        float lg[NEXP];
#pragma unroll
        for (int e = 0; e < NEXP; ++e) {
            int es = swz_e(tk, e);
            lg[e] = ((red[0][tk][es] + red[1][tk][es]) +
                     (red[2][tk][es] + red[3][tk][es])) + Bg[e];
        }
        float* outL = out + (size_t)t * NEXP;
#pragma unroll
        for (int e = 0; e < NEXP; e += 4) {
            float4 v = make_float4(lg[e], lg[e+1], lg[e+2], lg[e+3]);
            *(float4*)(outL + e) = v;
        }
        float mx = lg[0];
#pragma unroll
        for (int e = 1; e < NEXP; ++e) mx = fmaxf(mx, lg[e]);
        float S = 0.f;
#pragma unroll
        for (int e = 0; e < NEXP; ++e) { lg[e] = expf(lg[e] - mx); S += lg[e]; }
#pragma unroll
        for (int e = 0; e < NEXP; ++e) lg[e] = lg[e] / S;

        float v1 = lg[0]; int i1 = 0;
        float v2 = -1.0f; int i2 = 0;
#pragma unroll
        for (int e = 1; e < NEXP; ++e) {
            float rv = lg[e];
            bool g1 = rv > v1;
            bool g2 = rv > v2;
            float nv2 = g1 ? v1 : (g2 ? rv : v2);
            int   ni2 = g1 ? i1 : (g2 ? e  : i2);
            v2 = nv2; i2 = ni2;
            v1 = g1 ? rv : v1;
            i1 = g1 ? e  : i1;
        }
        float den = v1 + v2;
        float w1 = v1 / den, w2 = v2 / den;

        float* outW = out + (size_t)T_TOK * NEXP;
        float* outS = outW + (size_t)T_TOK * 2;
        float* outM = outS + (size_t)T_TOK * 2;
        outW[2*t+0] = w1;        outW[2*t+1] = w2;
        outS[2*t+0] = (float)i1; outS[2*t+1] = (float)i2;

        float* mrow = outM + (size_t)t * 2 * NEXP;
#pragma unroll
        for (int e = 0; e < NEXP; e += 4) {
            float4 a = make_float4(e+0==i1?1.f:0.f, e+1==i1?1.f:0.f,
                                   e+2==i1?1.f:0.f, e+3==i1?1.f:0.f);
            *(float4*)(mrow + e) = a;
            float4 b = make_float4(e+0==i2?1.f:0.f, e+1==i2?1.f:0.f,
                                   e+2==i2?1.f:0.f, e+3==i2?1.f:0.f);
            *(float4*)(mrow + NEXP + e) = b;
        }
    }
}

extern "C" void kernel_launch(void* const* d_in, const int* in_sizes, int n_in,
                              void* d_out, int out_size, void* d_ws, size_t ws_size,
                              hipStream_t stream)
{
    const float* X = (const float*)d_in[0];
    const float* W = (const float*)d_in[1];
    const float* B = (const float*)d_in[2];
    float* out     = (float*)d_out;

    dim3 grid(T_TOK / TPB);   // 256 blocks, 1 per CU
    dim3 block(512);          // 8 waves
    hipLaunchKernelGGL(moe_router_mfma, grid, block, 0, stream, X, W, B, out);
}